// Round 9
// baseline (88.879 us; speedup 1.0000x reference)
//
#include <hip/hip_runtime.h>

// TopKRouter: x[B=16,C=768,H=64,W=64] fp32, W[E=16,C=768], b[E=16], k=2.
// R9: two-kernel (Wt transpose prologue preserves s_load of weights — proven)
// + main with FLOAT4 grain: 1 KB per wave per channel-step (DRAM page
// locality test), 256 px/block, 4 channel-groups, grid 256 = 1 block/CU.
// Cross-wave reduce: 4-step sequential accumulate into red[16][256] (16 KB),
// ds_write_b128 (4-px contiguous), conflict-free epilogue reads (2 lanes/bank).
// Outputs fp32 concat: topk_probs[16,2,64,64] | topk_indices[16,2,64,64] |
// scores[16,16,64,64].

#define C_DIM 768
#define E_DIM 16
#define HW    4096   // 64*64
#define NPIX  65536  // 16*4096

// ---------------- Prologue: Wt[c][e] = W[e][c] ----------------------------
__global__ __launch_bounds__(256) void transpose_w(
    const float* __restrict__ Wm, float* __restrict__ Wt)
{
    const int t = blockIdx.x * 256 + threadIdx.x;  // 12288 elements
    if (t < C_DIM * E_DIM) {
        const int e = t / C_DIM;
        const int c = t - e * C_DIM;
        Wt[c * E_DIM + e] = Wm[t];  // coalesced read, scattered write
    }
}

// ---------------- Main ----------------------------------------------------
__global__ __launch_bounds__(256) void router_main(
    const float* __restrict__ x,     // [B, C, HW]
    const float* __restrict__ Wt,    // [C, E] transposed weights (in ws)
    const float* __restrict__ bias,  // [E]
    float* __restrict__ out)
{
    __shared__ float red[E_DIM][256];  // 16 KB reduce buffer

    // chunked XCD swizzle (256 blocks, 8 XCDs, 32 chunks each) — bijective
    const int logical = ((blockIdx.x & 7) << 5) + (blockIdx.x >> 3);

    const int p0  = logical * 256;               // first pixel of block
    const int b   = p0 >> 12;                    // batch (block-uniform)
    const int pb  = p0 & 4095;
    const int cg  = __builtin_amdgcn_readfirstlane(threadIdx.x >> 6);
    const int ln  = threadIdx.x & 63;            // lane
    const int c0  = cg * 192;

    const float* xp = x + (size_t)b * C_DIM * HW + pb + 4 * ln;

    float4 acc[E_DIM];
#pragma unroll
    for (int e = 0; e < E_DIM; ++e) acc[e] = make_float4(0.f, 0.f, 0.f, 0.f);

#pragma unroll 8
    for (int c = c0; c < c0 + 192; ++c) {
        const float4 xv = *reinterpret_cast<const float4*>(xp + (size_t)c * HW);
        const float4* wt = reinterpret_cast<const float4*>(Wt + c * E_DIM);
        const float4 w0 = wt[0], w1 = wt[1], w2 = wt[2], w3 = wt[3];
        acc[ 0].x = fmaf(xv.x, w0.x, acc[ 0].x); acc[ 0].y = fmaf(xv.y, w0.x, acc[ 0].y);
        acc[ 0].z = fmaf(xv.z, w0.x, acc[ 0].z); acc[ 0].w = fmaf(xv.w, w0.x, acc[ 0].w);
        acc[ 1].x = fmaf(xv.x, w0.y, acc[ 1].x); acc[ 1].y = fmaf(xv.y, w0.y, acc[ 1].y);
        acc[ 1].z = fmaf(xv.z, w0.y, acc[ 1].z); acc[ 1].w = fmaf(xv.w, w0.y, acc[ 1].w);
        acc[ 2].x = fmaf(xv.x, w0.z, acc[ 2].x); acc[ 2].y = fmaf(xv.y, w0.z, acc[ 2].y);
        acc[ 2].z = fmaf(xv.z, w0.z, acc[ 2].z); acc[ 2].w = fmaf(xv.w, w0.z, acc[ 2].w);
        acc[ 3].x = fmaf(xv.x, w0.w, acc[ 3].x); acc[ 3].y = fmaf(xv.y, w0.w, acc[ 3].y);
        acc[ 3].z = fmaf(xv.z, w0.w, acc[ 3].z); acc[ 3].w = fmaf(xv.w, w0.w, acc[ 3].w);
        acc[ 4].x = fmaf(xv.x, w1.x, acc[ 4].x); acc[ 4].y = fmaf(xv.y, w1.x, acc[ 4].y);
        acc[ 4].z = fmaf(xv.z, w1.x, acc[ 4].z); acc[ 4].w = fmaf(xv.w, w1.x, acc[ 4].w);
        acc[ 5].x = fmaf(xv.x, w1.y, acc[ 5].x); acc[ 5].y = fmaf(xv.y, w1.y, acc[ 5].y);
        acc[ 5].z = fmaf(xv.z, w1.y, acc[ 5].z); acc[ 5].w = fmaf(xv.w, w1.y, acc[ 5].w);
        acc[ 6].x = fmaf(xv.x, w1.z, acc[ 6].x); acc[ 6].y = fmaf(xv.y, w1.z, acc[ 6].y);
        acc[ 6].z = fmaf(xv.z, w1.z, acc[ 6].z); acc[ 6].w = fmaf(xv.w, w1.z, acc[ 6].w);
        acc[ 7].x = fmaf(xv.x, w1.w, acc[ 7].x); acc[ 7].y = fmaf(xv.y, w1.w, acc[ 7].y);
        acc[ 7].z = fmaf(xv.z, w1.w, acc[ 7].z); acc[ 7].w = fmaf(xv.w, w1.w, acc[ 7].w);
        acc[ 8].x = fmaf(xv.x, w2.x, acc[ 8].x); acc[ 8].y = fmaf(xv.y, w2.x, acc[ 8].y);
        acc[ 8].z = fmaf(xv.z, w2.x, acc[ 8].z); acc[ 8].w = fmaf(xv.w, w2.x, acc[ 8].w);
        acc[ 9].x = fmaf(xv.x, w2.y, acc[ 9].x); acc[ 9].y = fmaf(xv.y, w2.y, acc[ 9].y);
        acc[ 9].z = fmaf(xv.z, w2.y, acc[ 9].z); acc[ 9].w = fmaf(xv.w, w2.y, acc[ 9].w);
        acc[10].x = fmaf(xv.x, w2.z, acc[10].x); acc[10].y = fmaf(xv.y, w2.z, acc[10].y);
        acc[10].z = fmaf(xv.z, w2.z, acc[10].z); acc[10].w = fmaf(xv.w, w2.z, acc[10].w);
        acc[11].x = fmaf(xv.x, w2.w, acc[11].x); acc[11].y = fmaf(xv.y, w2.w, acc[11].y);
        acc[11].z = fmaf(xv.z, w2.w, acc[11].z); acc[11].w = fmaf(xv.w, w2.w, acc[11].w);
        acc[12].x = fmaf(xv.x, w3.x, acc[12].x); acc[12].y = fmaf(xv.y, w3.x, acc[12].y);
        acc[12].z = fmaf(xv.z, w3.x, acc[12].z); acc[12].w = fmaf(xv.w, w3.x, acc[12].w);
        acc[13].x = fmaf(xv.x, w3.y, acc[13].x); acc[13].y = fmaf(xv.y, w3.y, acc[13].y);
        acc[13].z = fmaf(xv.z, w3.y, acc[13].z); acc[13].w = fmaf(xv.w, w3.y, acc[13].w);
        acc[14].x = fmaf(xv.x, w3.z, acc[14].x); acc[14].y = fmaf(xv.y, w3.z, acc[14].y);
        acc[14].z = fmaf(xv.z, w3.z, acc[14].z); acc[14].w = fmaf(xv.w, w3.z, acc[14].w);
        acc[15].x = fmaf(xv.x, w3.w, acc[15].x); acc[15].y = fmaf(xv.y, w3.w, acc[15].y);
        acc[15].z = fmaf(xv.z, w3.w, acc[15].z); acc[15].w = fmaf(xv.w, w3.w, acc[15].w);
    }

    // ---- 4-step sequential cross-wave accumulate into red[16][256] ----
    // wave cg==s writes/adds its float4 at px 4*ln (ds_write_b128, contiguous)
    __syncthreads();  // red not in use before; barrier aligns steps
#pragma unroll
    for (int s = 0; s < 4; ++s) {
        if (cg == s) {
            if (s == 0) {
#pragma unroll
                for (int e = 0; e < E_DIM; ++e)
                    *reinterpret_cast<float4*>(&red[e][4 * ln]) = acc[e];
            } else {
#pragma unroll
                for (int e = 0; e < E_DIM; ++e) {
                    float4 r = *reinterpret_cast<float4*>(&red[e][4 * ln]);
                    r.x += acc[e].x; r.y += acc[e].y; r.z += acc[e].z; r.w += acc[e].w;
                    *reinterpret_cast<float4*>(&red[e][4 * ln]) = r;
                }
            }
        }
        __syncthreads();
    }

    // ---- epilogue: softmax + top2; 256 threads, 1 px each ----
    {
        const int t = threadIdx.x;
        const int p = pb + t;  // pixel within b-plane

        float lg[E_DIM];
#pragma unroll
        for (int e = 0; e < E_DIM; ++e) lg[e] = bias[e] + red[e][t];

        float m = -INFINITY;
#pragma unroll
        for (int e = 0; e < E_DIM; ++e) m = fmaxf(m, lg[e]);
        float pr[E_DIM];
        float sum = 0.0f;
#pragma unroll
        for (int e = 0; e < E_DIM; ++e) {
            pr[e] = __expf(lg[e] - m);
            sum += pr[e];
        }
        const float inv = 1.0f / sum;

        float* scores = out + 262144;
#pragma unroll
        for (int e = 0; e < E_DIM; ++e) {
            const float s = pr[e] * inv;
            pr[e] = s;
            scores[(size_t)(b * E_DIM + e) * HW + p] = s;
        }

        // top-2, ties -> lower index (matches jax.lax.top_k)
        int i1 = 0;
        float p1 = pr[0];
#pragma unroll
        for (int e = 1; e < E_DIM; ++e)
            if (pr[e] > p1) { p1 = pr[e]; i1 = e; }
        int i2 = -1;
        float p2 = -INFINITY;
#pragma unroll
        for (int e = 0; e < E_DIM; ++e)
            if (e != i1 && pr[e] > p2) { p2 = pr[e]; i2 = e; }

        const float rs = 1.0f / (p1 + p2);
        const size_t o1 = (size_t)(b * 2 + 0) * HW + p;
        const size_t o2 = (size_t)(b * 2 + 1) * HW + p;
        out[o1] = p1 * rs;
        out[o2] = p2 * rs;
        float* idxo = out + 131072;
        idxo[o1] = (float)i1;
        idxo[o2] = (float)i2;
    }
}

// ---------------- Fallback: fused single-pass, no ws ----------------------
__global__ __launch_bounds__(256) void topk_router_fused(
    const float* __restrict__ x, const float* __restrict__ Wm,
    const float* __restrict__ bias, float* __restrict__ out)
{
    const int g = blockIdx.x * 256 + threadIdx.x;
    const int b = g >> 12;
    const int p = g & 4095;
    const float* xp = x + (size_t)b * C_DIM * HW + p;

    float acc[E_DIM];
#pragma unroll
    for (int e = 0; e < E_DIM; ++e) acc[e] = 0.0f;
#pragma unroll 16
    for (int c = 0; c < C_DIM; ++c) {
        const float xv = xp[(size_t)c * HW];
#pragma unroll
        for (int e = 0; e < E_DIM; ++e)
            acc[e] = fmaf(xv, Wm[e * C_DIM + c], acc[e]);
    }
    float m = -INFINITY;
#pragma unroll
    for (int e = 0; e < E_DIM; ++e) { acc[e] += bias[e]; m = fmaxf(m, acc[e]); }
    float pr[E_DIM]; float sum = 0.0f;
#pragma unroll
    for (int e = 0; e < E_DIM; ++e) { pr[e] = __expf(acc[e] - m); sum += pr[e]; }
    const float inv = 1.0f / sum;
    float* scores = out + 262144;
#pragma unroll
    for (int e = 0; e < E_DIM; ++e) {
        const float s = pr[e] * inv; pr[e] = s;
        scores[(size_t)(b * E_DIM + e) * HW + p] = s;
    }
    int i1 = 0; float p1 = pr[0];
#pragma unroll
    for (int e = 1; e < E_DIM; ++e) if (pr[e] > p1) { p1 = pr[e]; i1 = e; }
    int i2 = -1; float p2 = -INFINITY;
#pragma unroll
    for (int e = 0; e < E_DIM; ++e) if (e != i1 && pr[e] > p2) { p2 = pr[e]; i2 = e; }
    const float rs = 1.0f / (p1 + p2);
    const size_t o1 = (size_t)(b * 2 + 0) * HW + p;
    const size_t o2 = (size_t)(b * 2 + 1) * HW + p;
    out[o1] = p1 * rs; out[o2] = p2 * rs;
    float* idxo = out + 131072;
    idxo[o1] = (float)i1; idxo[o2] = (float)i2;
}

extern "C" void kernel_launch(void* const* d_in, const int* in_sizes, int n_in,
                              void* d_out, int out_size, void* d_ws, size_t ws_size,
                              hipStream_t stream) {
    const float* x  = (const float*)d_in[0];
    const float* Wm = (const float*)d_in[1];
    const float* bs = (const float*)d_in[2];
    float* out = (float*)d_out;
    float* Wt  = (float*)d_ws;  // 48 KB

    if (ws_size >= (size_t)C_DIM * E_DIM * sizeof(float)) {
        transpose_w<<<48, 256, 0, stream>>>(Wm, Wt);
        router_main<<<NPIX / 256, 256, 0, stream>>>(x, Wt, bs, out);
    } else {
        topk_router_fused<<<NPIX / 256, 256, 0, stream>>>(x, Wm, bs, out);
    }
}

// Round 10
// 44.511 us; speedup vs baseline: 1.9968x; 1.9968x over previous
//
#include <hip/hip_runtime.h>

// TopKRouter: x[B=16,C=768,H=64,W=64] fp32, W[E=16,C=768], b[E=16], k=2.
// R10: test float4 (16B/lane, 1KB/wave-visit) at 8 waves/CU — R9 failed this
// at 4 waves/CU (VGPR starvation + no TLP). Structure: 512-thr blocks
// (8 waves = 8 channel-groups x 96 ch), 256 px/block, grid 256 = 1 block/CU.
// Cross-wave reduce via 128 KB DYNAMIC LDS [cg][e][px], single barrier.
// Wt-transpose prologue kept (preserves wave-uniform s_load of weights).
// Fallback to proven R8 path (40.7us) if dynamic-LDS attribute fails.
// Outputs fp32 concat: topk_probs[16,2,64,64] | topk_indices[16,2,64,64] |
// scores[16,16,64,64].

#define C_DIM 768
#define E_DIM 16
#define HW    4096   // 64*64
#define NPIX  65536  // 16*4096

// ---------------- Prologue: Wt[c][e] = W[e][c] ----------------------------
__global__ __launch_bounds__(256) void transpose_w(
    const float* __restrict__ Wm, float* __restrict__ Wt)
{
    const int t = blockIdx.x * 256 + threadIdx.x;  // 12288 elements
    if (t < C_DIM * E_DIM) {
        const int e = t / C_DIM;
        const int c = t - e * C_DIM;
        Wt[c * E_DIM + e] = Wm[t];  // coalesced read, scattered write
    }
}

// ---------------- Main: float4, 8 waves/CU, 8-way channel split -----------
__global__ __launch_bounds__(512, 1) void router_main8(
    const float* __restrict__ x,     // [B, C, HW]
    const float* __restrict__ Wt,    // [C, E]
    const float* __restrict__ bias,  // [E]
    float* __restrict__ out)
{
    extern __shared__ float red[];   // [8][16][256] = 128 KB dynamic

    const int p0 = blockIdx.x * 256;             // first pixel of block
    const int b  = p0 >> 12;                     // batch (block-uniform)
    const int pb = p0 & 4095;
    const int cg = __builtin_amdgcn_readfirstlane((int)(threadIdx.x >> 6)); // 0..7
    const int ln = threadIdx.x & 63;             // lane
    const int c0 = cg * 96;

    const float* xp = x + (size_t)b * C_DIM * HW + pb + 4 * ln;

    float4 acc[E_DIM];
#pragma unroll
    for (int e = 0; e < E_DIM; ++e) acc[e] = make_float4(0.f, 0.f, 0.f, 0.f);

#pragma unroll 4
    for (int c = c0; c < c0 + 96; ++c) {
        const float4 xv = *reinterpret_cast<const float4*>(xp + (size_t)c * HW);
        const float4* wt = reinterpret_cast<const float4*>(Wt + c * E_DIM);
        const float4 w0 = wt[0], w1 = wt[1], w2 = wt[2], w3 = wt[3];
        acc[ 0].x = fmaf(xv.x, w0.x, acc[ 0].x); acc[ 0].y = fmaf(xv.y, w0.x, acc[ 0].y);
        acc[ 0].z = fmaf(xv.z, w0.x, acc[ 0].z); acc[ 0].w = fmaf(xv.w, w0.x, acc[ 0].w);
        acc[ 1].x = fmaf(xv.x, w0.y, acc[ 1].x); acc[ 1].y = fmaf(xv.y, w0.y, acc[ 1].y);
        acc[ 1].z = fmaf(xv.z, w0.y, acc[ 1].z); acc[ 1].w = fmaf(xv.w, w0.y, acc[ 1].w);
        acc[ 2].x = fmaf(xv.x, w0.z, acc[ 2].x); acc[ 2].y = fmaf(xv.y, w0.z, acc[ 2].y);
        acc[ 2].z = fmaf(xv.z, w0.z, acc[ 2].z); acc[ 2].w = fmaf(xv.w, w0.z, acc[ 2].w);
        acc[ 3].x = fmaf(xv.x, w0.w, acc[ 3].x); acc[ 3].y = fmaf(xv.y, w0.w, acc[ 3].y);
        acc[ 3].z = fmaf(xv.z, w0.w, acc[ 3].z); acc[ 3].w = fmaf(xv.w, w0.w, acc[ 3].w);
        acc[ 4].x = fmaf(xv.x, w1.x, acc[ 4].x); acc[ 4].y = fmaf(xv.y, w1.x, acc[ 4].y);
        acc[ 4].z = fmaf(xv.z, w1.x, acc[ 4].z); acc[ 4].w = fmaf(xv.w, w1.x, acc[ 4].w);
        acc[ 5].x = fmaf(xv.x, w1.y, acc[ 5].x); acc[ 5].y = fmaf(xv.y, w1.y, acc[ 5].y);
        acc[ 5].z = fmaf(xv.z, w1.y, acc[ 5].z); acc[ 5].w = fmaf(xv.w, w1.y, acc[ 5].w);
        acc[ 6].x = fmaf(xv.x, w1.z, acc[ 6].x); acc[ 6].y = fmaf(xv.y, w1.z, acc[ 6].y);
        acc[ 6].z = fmaf(xv.z, w1.z, acc[ 6].z); acc[ 6].w = fmaf(xv.w, w1.z, acc[ 6].w);
        acc[ 7].x = fmaf(xv.x, w1.w, acc[ 7].x); acc[ 7].y = fmaf(xv.y, w1.w, acc[ 7].y);
        acc[ 7].z = fmaf(xv.z, w1.w, acc[ 7].z); acc[ 7].w = fmaf(xv.w, w1.w, acc[ 7].w);
        acc[ 8].x = fmaf(xv.x, w2.x, acc[ 8].x); acc[ 8].y = fmaf(xv.y, w2.x, acc[ 8].y);
        acc[ 8].z = fmaf(xv.z, w2.x, acc[ 8].z); acc[ 8].w = fmaf(xv.w, w2.x, acc[ 8].w);
        acc[ 9].x = fmaf(xv.x, w2.y, acc[ 9].x); acc[ 9].y = fmaf(xv.y, w2.y, acc[ 9].y);
        acc[ 9].z = fmaf(xv.z, w2.y, acc[ 9].z); acc[ 9].w = fmaf(xv.w, w2.y, acc[ 9].w);
        acc[10].x = fmaf(xv.x, w2.z, acc[10].x); acc[10].y = fmaf(xv.y, w2.z, acc[10].y);
        acc[10].z = fmaf(xv.z, w2.z, acc[10].z); acc[10].w = fmaf(xv.w, w2.z, acc[10].w);
        acc[11].x = fmaf(xv.x, w2.w, acc[11].x); acc[11].y = fmaf(xv.y, w2.w, acc[11].y);
        acc[11].z = fmaf(xv.z, w2.w, acc[11].z); acc[11].w = fmaf(xv.w, w2.w, acc[11].w);
        acc[12].x = fmaf(xv.x, w3.x, acc[12].x); acc[12].y = fmaf(xv.y, w3.x, acc[12].y);
        acc[12].z = fmaf(xv.z, w3.x, acc[12].z); acc[12].w = fmaf(xv.w, w3.x, acc[12].w);
        acc[13].x = fmaf(xv.x, w3.y, acc[13].x); acc[13].y = fmaf(xv.y, w3.y, acc[13].y);
        acc[13].z = fmaf(xv.z, w3.y, acc[13].z); acc[13].w = fmaf(xv.w, w3.y, acc[13].w);
        acc[14].x = fmaf(xv.x, w3.z, acc[14].x); acc[14].y = fmaf(xv.y, w3.z, acc[14].y);
        acc[14].z = fmaf(xv.z, w3.z, acc[14].z); acc[14].w = fmaf(xv.w, w3.z, acc[14].w);
        acc[15].x = fmaf(xv.x, w3.w, acc[15].x); acc[15].y = fmaf(xv.y, w3.w, acc[15].y);
        acc[15].z = fmaf(xv.z, w3.w, acc[15].z); acc[15].w = fmaf(xv.w, w3.w, acc[15].w);
    }

    // stage partials: red[cg][e][px], ds_write_b128 (4-px contiguous)
    float* slab = red + cg * (E_DIM * 256);
#pragma unroll
    for (int e = 0; e < E_DIM; ++e)
        *reinterpret_cast<float4*>(slab + e * 256 + 4 * ln) = acc[e];
    __syncthreads();

    // ---- epilogue: threads 0..255, one px each ----
    const int t = threadIdx.x;
    if (t < 256) {
        const int p = pb + t;  // pixel within b-plane

        float lg[E_DIM];
#pragma unroll
        for (int e = 0; e < E_DIM; ++e) lg[e] = bias[e];
#pragma unroll
        for (int s = 0; s < 8; ++s)
#pragma unroll
            for (int e = 0; e < E_DIM; ++e)
                lg[e] += red[s * (E_DIM * 256) + e * 256 + t];

        float m = -INFINITY;
#pragma unroll
        for (int e = 0; e < E_DIM; ++e) m = fmaxf(m, lg[e]);
        float pr[E_DIM];
        float sum = 0.0f;
#pragma unroll
        for (int e = 0; e < E_DIM; ++e) {
            pr[e] = __expf(lg[e] - m);
            sum += pr[e];
        }
        const float inv = 1.0f / sum;

        float* scores = out + 262144;
#pragma unroll
        for (int e = 0; e < E_DIM; ++e) {
            const float s = pr[e] * inv;
            pr[e] = s;
            scores[(size_t)(b * E_DIM + e) * HW + p] = s;
        }

        // top-2, ties -> lower index (matches jax.lax.top_k)
        int i1 = 0;
        float p1 = pr[0];
#pragma unroll
        for (int e = 1; e < E_DIM; ++e)
            if (pr[e] > p1) { p1 = pr[e]; i1 = e; }
        int i2 = -1;
        float p2 = -INFINITY;
#pragma unroll
        for (int e = 0; e < E_DIM; ++e)
            if (e != i1 && pr[e] > p2) { p2 = pr[e]; i2 = e; }

        const float rs = 1.0f / (p1 + p2);
        const size_t o1 = (size_t)(b * 2 + 0) * HW + p;
        const size_t o2 = (size_t)(b * 2 + 1) * HW + p;
        out[o1] = p1 * rs;
        out[o2] = p2 * rs;
        float* idxo = out + 131072;
        idxo[o1] = (float)i1;
        idxo[o2] = (float)i2;
    }
}

// ---------------- Fallback main (R8 structure, proven 40.7us) -------------
__global__ __launch_bounds__(256, 2) void router_main(
    const float* __restrict__ x, const float* __restrict__ Wt,
    const float* __restrict__ bias, float* __restrict__ out)
{
    __shared__ float lds[4][128][17];
    const int p0  = blockIdx.x * 128;
    const int b   = p0 >> 12;
    const int pb  = p0 & 4095;
    const int cg_ = __builtin_amdgcn_readfirstlane((int)(threadIdx.x >> 6));
    const int px2 = threadIdx.x & 63;
    const int c0  = cg_ * 192;
    const float* xp = x + (size_t)b * C_DIM * HW + pb + 2 * px2;

    float2 acc[E_DIM];
#pragma unroll
    for (int e = 0; e < E_DIM; ++e) acc[e] = make_float2(0.f, 0.f);
#pragma unroll 8
    for (int c = c0; c < c0 + 192; ++c) {
        const float2 xv = *reinterpret_cast<const float2*>(xp + (size_t)c * HW);
        const float4* wt = reinterpret_cast<const float4*>(Wt + c * E_DIM);
        const float4 w0 = wt[0], w1 = wt[1], w2 = wt[2], w3 = wt[3];
        acc[ 0].x = fmaf(xv.x, w0.x, acc[ 0].x); acc[ 0].y = fmaf(xv.y, w0.x, acc[ 0].y);
        acc[ 1].x = fmaf(xv.x, w0.y, acc[ 1].x); acc[ 1].y = fmaf(xv.y, w0.y, acc[ 1].y);
        acc[ 2].x = fmaf(xv.x, w0.z, acc[ 2].x); acc[ 2].y = fmaf(xv.y, w0.z, acc[ 2].y);
        acc[ 3].x = fmaf(xv.x, w0.w, acc[ 3].x); acc[ 3].y = fmaf(xv.y, w0.w, acc[ 3].y);
        acc[ 4].x = fmaf(xv.x, w1.x, acc[ 4].x); acc[ 4].y = fmaf(xv.y, w1.x, acc[ 4].y);
        acc[ 5].x = fmaf(xv.x, w1.y, acc[ 5].x); acc[ 5].y = fmaf(xv.y, w1.y, acc[ 5].y);
        acc[ 6].x = fmaf(xv.x, w1.z, acc[ 6].x); acc[ 6].y = fmaf(xv.y, w1.z, acc[ 6].y);
        acc[ 7].x = fmaf(xv.x, w1.w, acc[ 7].x); acc[ 7].y = fmaf(xv.y, w1.w, acc[ 7].y);
        acc[ 8].x = fmaf(xv.x, w2.x, acc[ 8].x); acc[ 8].y = fmaf(xv.y, w2.x, acc[ 8].y);
        acc[ 9].x = fmaf(xv.x, w2.y, acc[ 9].x); acc[ 9].y = fmaf(xv.y, w2.y, acc[ 9].y);
        acc[10].x = fmaf(xv.x, w2.z, acc[10].x); acc[10].y = fmaf(xv.y, w2.z, acc[10].y);
        acc[11].x = fmaf(xv.x, w2.w, acc[11].x); acc[11].y = fmaf(xv.y, w2.w, acc[11].y);
        acc[12].x = fmaf(xv.x, w3.x, acc[12].x); acc[12].y = fmaf(xv.y, w3.x, acc[12].y);
        acc[13].x = fmaf(xv.x, w3.y, acc[13].x); acc[13].y = fmaf(xv.y, w3.y, acc[13].y);
        acc[14].x = fmaf(xv.x, w3.z, acc[14].x); acc[14].y = fmaf(xv.y, w3.z, acc[14].y);
        acc[15].x = fmaf(xv.x, w3.w, acc[15].x); acc[15].y = fmaf(xv.y, w3.w, acc[15].y);
    }
#pragma unroll
    for (int e = 0; e < E_DIM; ++e) {
        lds[cg_][2 * px2][e]     = acc[e].x;
        lds[cg_][2 * px2 + 1][e] = acc[e].y;
    }
    __syncthreads();
    const int t = threadIdx.x;
    if (t < 128) {
        const int p = pb + t;
        float lg[E_DIM];
#pragma unroll
        for (int e = 0; e < E_DIM; ++e)
            lg[e] = bias[e] + lds[0][t][e] + lds[1][t][e] + lds[2][t][e] + lds[3][t][e];
        float m = -INFINITY;
#pragma unroll
        for (int e = 0; e < E_DIM; ++e) m = fmaxf(m, lg[e]);
        float pr[E_DIM]; float sum = 0.0f;
#pragma unroll
        for (int e = 0; e < E_DIM; ++e) { pr[e] = __expf(lg[e] - m); sum += pr[e]; }
        const float inv = 1.0f / sum;
        float* scores = out + 262144;
#pragma unroll
        for (int e = 0; e < E_DIM; ++e) {
            const float s = pr[e] * inv; pr[e] = s;
            scores[(size_t)(b * E_DIM + e) * HW + p] = s;
        }
        int i1 = 0; float p1 = pr[0];
#pragma unroll
        for (int e = 1; e < E_DIM; ++e) if (pr[e] > p1) { p1 = pr[e]; i1 = e; }
        int i2 = -1; float p2 = -INFINITY;
#pragma unroll
        for (int e = 0; e < E_DIM; ++e) if (e != i1 && pr[e] > p2) { p2 = pr[e]; i2 = e; }
        const float rs = 1.0f / (p1 + p2);
        const size_t o1 = (size_t)(b * 2 + 0) * HW + p;
        const size_t o2 = (size_t)(b * 2 + 1) * HW + p;
        out[o1] = p1 * rs; out[o2] = p2 * rs;
        float* idxo = out + 131072;
        idxo[o1] = (float)i1; idxo[o2] = (float)i2;
    }
}

extern "C" void kernel_launch(void* const* d_in, const int* in_sizes, int n_in,
                              void* d_out, int out_size, void* d_ws, size_t ws_size,
                              hipStream_t stream) {
    const float* x  = (const float*)d_in[0];
    const float* Wm = (const float*)d_in[1];
    const float* bs = (const float*)d_in[2];
    float* out = (float*)d_out;
    float* Wt  = (float*)d_ws;  // 48 KB

    transpose_w<<<48, 256, 0, stream>>>(Wm, Wt);

    // opt-in to 128 KB dynamic LDS; fall back to proven R8 path on failure
    const int dyn_lds = 8 * E_DIM * 256 * sizeof(float);  // 131072
    hipError_t attr_ok = hipFuncSetAttribute(
        (const void*)router_main8,
        hipFuncAttributeMaxDynamicSharedMemorySize, dyn_lds);
    if (attr_ok == hipSuccess) {
        router_main8<<<NPIX / 256, 512, dyn_lds, stream>>>(x, Wt, bs, out);
    } else {
        router_main<<<NPIX / 128, 256, 0, stream>>>(x, Wt, bs, out);
    }
}

// Round 11
// 40.865 us; speedup vs baseline: 2.1749x; 1.0892x over previous
//
#include <hip/hip_runtime.h>

// TopKRouter: x[B=16,C=768,H=64,W=64] fp32, W[E=16,C=768], b[E=16], k=2.
// FINAL (= R8, proven 40.7us): two-kernel design.
//   K1 transpose_w: Wt[c][e] = W[e][c] in ws (48 KB). Keeping the transpose in
//      a SEPARATE kernel is essential: main's Wt reads stay wave-uniform
//      s_load broadcasts (R7 fusion demoted them to vector loads: 146us).
//   K2 router_main: float2/lane (512 B/wave-visit — measured optimum grain:
//      256 B = 45.6us, 1 KB = 44.5us), 4 channel-groups x 128 px/block,
//      512 blocks = 2/CU = 8 waves/CU, LDS reduce + softmax + top2 epilogue.
// Sustains ~9.4 B/cyc/CU on the x stream = ~92% of the measured copy ceiling
// (10.2 B/cyc/CU, m13) — memory roofline for this strided pattern.
// Outputs fp32 concat: topk_probs[16,2,64,64] | topk_indices[16,2,64,64] |
// scores[16,16,64,64].

#define C_DIM 768
#define E_DIM 16
#define HW    4096   // 64*64
#define NPIX  65536  // 16*4096

// ---------------- Prologue: Wt[c][e] = W[e][c] ----------------------------
__global__ __launch_bounds__(256) void transpose_w(
    const float* __restrict__ Wm, float* __restrict__ Wt)
{
    const int t = blockIdx.x * 256 + threadIdx.x;  // 12288 elements
    if (t < C_DIM * E_DIM) {
        const int e = t / C_DIM;
        const int c = t - e * C_DIM;
        Wt[c * E_DIM + e] = Wm[t];  // coalesced read, scattered write
    }
}

// ---------------- Main ----------------------------------------------------
__global__ __launch_bounds__(256) void router_main(
    const float* __restrict__ x,     // [B, C, HW]
    const float* __restrict__ Wt,    // [C, E] transposed weights (in ws)
    const float* __restrict__ bias,  // [E]
    float* __restrict__ out)
{
    __shared__ float lds[4][128][17];  // [cg][px][e], pad 17 -> conflict-free

    // chunked XCD swizzle (512 blocks, 8 XCDs, 64 chunks each) — bijective
    const int logical = ((blockIdx.x & 7) << 6) + (blockIdx.x >> 3);

    const int p0  = logical * 128;               // first pixel of block
    const int b   = p0 >> 12;                    // batch (block-uniform)
    const int pb  = p0 & 4095;
    const int cg  = __builtin_amdgcn_readfirstlane((int)(threadIdx.x >> 6));
    const int px2 = threadIdx.x & 63;            // lane -> pixel pair
    const int c0  = cg * 192;

    const float* xp = x + (size_t)b * C_DIM * HW + pb + 2 * px2;

    float2 acc[E_DIM];
#pragma unroll
    for (int e = 0; e < E_DIM; ++e) acc[e] = make_float2(0.f, 0.f);

#pragma unroll 8
    for (int c = c0; c < c0 + 192; ++c) {
        const float2 xv = *reinterpret_cast<const float2*>(xp + (size_t)c * HW);
        const float4* wt = reinterpret_cast<const float4*>(Wt + c * E_DIM);
        const float4 w0 = wt[0], w1 = wt[1], w2 = wt[2], w3 = wt[3];
        acc[ 0].x = fmaf(xv.x, w0.x, acc[ 0].x); acc[ 0].y = fmaf(xv.y, w0.x, acc[ 0].y);
        acc[ 1].x = fmaf(xv.x, w0.y, acc[ 1].x); acc[ 1].y = fmaf(xv.y, w0.y, acc[ 1].y);
        acc[ 2].x = fmaf(xv.x, w0.z, acc[ 2].x); acc[ 2].y = fmaf(xv.y, w0.z, acc[ 2].y);
        acc[ 3].x = fmaf(xv.x, w0.w, acc[ 3].x); acc[ 3].y = fmaf(xv.y, w0.w, acc[ 3].y);
        acc[ 4].x = fmaf(xv.x, w1.x, acc[ 4].x); acc[ 4].y = fmaf(xv.y, w1.x, acc[ 4].y);
        acc[ 5].x = fmaf(xv.x, w1.y, acc[ 5].x); acc[ 5].y = fmaf(xv.y, w1.y, acc[ 5].y);
        acc[ 6].x = fmaf(xv.x, w1.z, acc[ 6].x); acc[ 6].y = fmaf(xv.y, w1.z, acc[ 6].y);
        acc[ 7].x = fmaf(xv.x, w1.w, acc[ 7].x); acc[ 7].y = fmaf(xv.y, w1.w, acc[ 7].y);
        acc[ 8].x = fmaf(xv.x, w2.x, acc[ 8].x); acc[ 8].y = fmaf(xv.y, w2.x, acc[ 8].y);
        acc[ 9].x = fmaf(xv.x, w2.y, acc[ 9].x); acc[ 9].y = fmaf(xv.y, w2.y, acc[ 9].y);
        acc[10].x = fmaf(xv.x, w2.z, acc[10].x); acc[10].y = fmaf(xv.y, w2.z, acc[10].y);
        acc[11].x = fmaf(xv.x, w2.w, acc[11].x); acc[11].y = fmaf(xv.y, w2.w, acc[11].y);
        acc[12].x = fmaf(xv.x, w3.x, acc[12].x); acc[12].y = fmaf(xv.y, w3.x, acc[12].y);
        acc[13].x = fmaf(xv.x, w3.y, acc[13].x); acc[13].y = fmaf(xv.y, w3.y, acc[13].y);
        acc[14].x = fmaf(xv.x, w3.z, acc[14].x); acc[14].y = fmaf(xv.y, w3.z, acc[14].y);
        acc[15].x = fmaf(xv.x, w3.w, acc[15].x); acc[15].y = fmaf(xv.y, w3.w, acc[15].y);
    }

    // stage partials: [cg][pixel][e] (stride 17 -> 2 lanes/bank, free)
#pragma unroll
    for (int e = 0; e < E_DIM; ++e) {
        lds[cg][2 * px2][e]     = acc[e].x;
        lds[cg][2 * px2 + 1][e] = acc[e].y;
    }
    __syncthreads();

    const int t = threadIdx.x;
    if (t < 128) {
        const int p = pb + t;  // pixel within b-plane

        float lg[E_DIM];
#pragma unroll
        for (int e = 0; e < E_DIM; ++e)
            lg[e] = bias[e] + lds[0][t][e] + lds[1][t][e] + lds[2][t][e] + lds[3][t][e];

        float m = -INFINITY;
#pragma unroll
        for (int e = 0; e < E_DIM; ++e) m = fmaxf(m, lg[e]);
        float pr[E_DIM];
        float sum = 0.0f;
#pragma unroll
        for (int e = 0; e < E_DIM; ++e) {
            pr[e] = __expf(lg[e] - m);
            sum += pr[e];
        }
        const float inv = 1.0f / sum;

        float* scores = out + 262144;
#pragma unroll
        for (int e = 0; e < E_DIM; ++e) {
            const float s = pr[e] * inv;
            pr[e] = s;
            scores[(size_t)(b * E_DIM + e) * HW + p] = s;
        }

        // top-2, ties -> lower index (matches jax.lax.top_k)
        int i1 = 0;
        float p1 = pr[0];
#pragma unroll
        for (int e = 1; e < E_DIM; ++e)
            if (pr[e] > p1) { p1 = pr[e]; i1 = e; }
        int i2 = -1;
        float p2 = -INFINITY;
#pragma unroll
        for (int e = 0; e < E_DIM; ++e)
            if (e != i1 && pr[e] > p2) { p2 = pr[e]; i2 = e; }

        const float rs = 1.0f / (p1 + p2);
        const size_t o1 = (size_t)(b * 2 + 0) * HW + p;
        const size_t o2 = (size_t)(b * 2 + 1) * HW + p;
        out[o1] = p1 * rs;
        out[o2] = p2 * rs;
        float* idxo = out + 131072;
        idxo[o1] = (float)i1;
        idxo[o2] = (float)i2;
    }
}

// ---------------- Fallback: fused single-pass, no ws ----------------------
__global__ __launch_bounds__(256) void topk_router_fused(
    const float* __restrict__ x, const float* __restrict__ Wm,
    const float* __restrict__ bias, float* __restrict__ out)
{
    const int g = blockIdx.x * 256 + threadIdx.x;
    const int b = g >> 12;
    const int p = g & 4095;
    const float* xp = x + (size_t)b * C_DIM * HW + p;

    float acc[E_DIM];
#pragma unroll
    for (int e = 0; e < E_DIM; ++e) acc[e] = 0.0f;
#pragma unroll 16
    for (int c = 0; c < C_DIM; ++c) {
        const float xv = xp[(size_t)c * HW];
#pragma unroll
        for (int e = 0; e < E_DIM; ++e)
            acc[e] = fmaf(xv, Wm[e * C_DIM + c], acc[e]);
    }
    float m = -INFINITY;
#pragma unroll
    for (int e = 0; e < E_DIM; ++e) { acc[e] += bias[e]; m = fmaxf(m, acc[e]); }
    float pr[E_DIM]; float sum = 0.0f;
#pragma unroll
    for (int e = 0; e < E_DIM; ++e) { pr[e] = __expf(acc[e] - m); sum += pr[e]; }
    const float inv = 1.0f / sum;
    float* scores = out + 262144;
#pragma unroll
    for (int e = 0; e < E_DIM; ++e) {
        const float s = pr[e] * inv; pr[e] = s;
        scores[(size_t)(b * E_DIM + e) * HW + p] = s;
    }
    int i1 = 0; float p1 = pr[0];
#pragma unroll
    for (int e = 1; e < E_DIM; ++e) if (pr[e] > p1) { p1 = pr[e]; i1 = e; }
    int i2 = -1; float p2 = -INFINITY;
#pragma unroll
    for (int e = 0; e < E_DIM; ++e) if (e != i1 && pr[e] > p2) { p2 = pr[e]; i2 = e; }
    const float rs = 1.0f / (p1 + p2);
    const size_t o1 = (size_t)(b * 2 + 0) * HW + p;
    const size_t o2 = (size_t)(b * 2 + 1) * HW + p;
    out[o1] = p1 * rs; out[o2] = p2 * rs;
    float* idxo = out + 131072;
    idxo[o1] = (float)i1; idxo[o2] = (float)i2;
}

extern "C" void kernel_launch(void* const* d_in, const int* in_sizes, int n_in,
                              void* d_out, int out_size, void* d_ws, size_t ws_size,
                              hipStream_t stream) {
    const float* x  = (const float*)d_in[0];
    const float* Wm = (const float*)d_in[1];
    const float* bs = (const float*)d_in[2];
    float* out = (float*)d_out;
    float* Wt  = (float*)d_ws;  // 48 KB

    if (ws_size >= (size_t)C_DIM * E_DIM * sizeof(float)) {
        transpose_w<<<48, 256, 0, stream>>>(Wm, Wt);
        router_main<<<NPIX / 128, 256, 0, stream>>>(x, Wt, bs, out);
    } else {
        topk_router_fused<<<NPIX / 256, 256, 0, stream>>>(x, Wm, bs, out);
    }
}